// Round 2
// baseline (89.158 us; speedup 1.0000x reference)
//
#include <hip/hip_runtime.h>
#include <hip/hip_bf16.h>

#define BB 16
#define SS 2048
#define DD 1024
#define HH 16
#define KK 31
#define HK 496

typedef float f32x4 __attribute__((ext_vector_type(4)));
typedef __bf16 bf16x8 __attribute__((ext_vector_type(8)));

__device__ __forceinline__ unsigned short f2bf(float x) {
  unsigned u = __float_as_uint(x);
  unsigned r = u + 0x7FFFu + ((u >> 16) & 1u);
  return (unsigned short)(r >> 16);
}

__device__ __forceinline__ void gll16(const void* g, void* l) {
  __builtin_amdgcn_global_load_lds(
      (const __attribute__((address_space(1))) unsigned int*)g,
      (__attribute__((address_space(3))) unsigned int*)l, 16, 0, 0);
}

// ---------------- prep: W_q (f32, D x 496) -> bf16 image, padded N=512.
// Per K-step (BK=32): granule-major [gr 0..3][c 0..511][e 0..7]
// Bimg[ks][gr][c][e] = Wp[ks*32 + gr*8 + e][c]
__global__ void prep_kernel(const float* __restrict__ Wq,
                            unsigned short* __restrict__ Bimg) {
  int idx = blockIdx.x * 256 + threadIdx.x;  // < 32*4*512*8 = 524288
  int e = idx & 7;
  int c = (idx >> 3) & 511;
  int gr = (idx >> 12) & 3;
  int ks = idx >> 14;
  int k = ks * 32 + gr * 8 + e;
  int h = c >> 5, j = c & 31;
  float v = (j < KK) ? Wq[k * HK + h * KK + j] : 0.f;
  Bimg[idx] = f2bf(v);
}

// ---------------- ksum: (B,S,H) = sum over 64 channels per head, f32
__global__ void ksum_kernel(const float* __restrict__ key,
                            float* __restrict__ ksum) {
  const int row = blockIdx.x;   // b*S + s
  const int tid = threadIdx.x;  // 0..255, 4 channels each
  const float4 v = reinterpret_cast<const float4*>(key + (size_t)row * DD)[tid];
  float p = v.x + v.y + v.z + v.w;
  p += __shfl_xor(p, 1);
  p += __shfl_xor(p, 2);
  p += __shfl_xor(p, 4);
  p += __shfl_xor(p, 8);
  if ((tid & 15) == 0) ksum[(size_t)row * HH + (tid >> 4)] = p;
}

// ---------------- fused GEMM (bf16 MFMA) + per-position conv + transpose
// BM=64, BN=512, BK=32, 8 waves (1x8), dbuf LDS 72KB -> 2 blocks/CU
__global__ __launch_bounds__(512, 4) void mca_kernel(
    const float* __restrict__ q, const float* __restrict__ bq,
    const float* __restrict__ convb, const float* __restrict__ ksum,
    const unsigned short* __restrict__ Bimg, float* __restrict__ out) {
  extern __shared__ char smem[];
  const int tid = threadIdx.x;
  const int w = tid >> 6, lane = tid & 63;
  const int g = lane >> 4, qq = lane & 15;
  const int bid = blockIdx.x;
  const int bb = bid >> 5;
  const int t0 = (bid & 31) << 6;

  char* const bB0 = smem;            // 32KB
  char* const bB1 = smem + 32768;    // 32KB
  char* const bA0 = smem + 65536;    // 4KB
  char* const bA1 = smem + 69632;    // 4KB

  const float* qblk = q + ((size_t)(bb * SS + t0)) * DD;

  f32x4 acc[4][4];
#pragma unroll
  for (int m = 0; m < 4; ++m)
#pragma unroll
    for (int n = 0; n < 4; ++n) acc[m][n] = (f32x4){0.f, 0.f, 0.f, 0.f};

  // A staging: thread -> (row, 16B quarter-row); rows 0..63, parts 0..7
  const int arow = tid >> 3;
  const int apart = tid & 7;
  const int ag = apart >> 1, ah = apart & 1;

  float4 rA;

  auto stageB = [&](char* dst, int ks) {
    // per step: 2048 granules of 16B; 4 per thread, linear order
    const char* src = (const char*)Bimg + (size_t)ks * 32768 + w * 1024 + lane * 16;
    char* d = dst + w * 1024;  // wave-uniform LDS base; HW adds lane*16
#pragma unroll
    for (int rr = 0; rr < 4; ++rr) gll16(src + rr * 8192, d + rr * 8192);
  };

  auto issueA = [&](int ks) {
    rA = *reinterpret_cast<const float4*>(qblk + (size_t)arow * DD + ks * 32 + apart * 4);
  };

  auto writeA = [&](char* dst) {
    unsigned u0 = (unsigned)f2bf(rA.x) | ((unsigned)f2bf(rA.y) << 16);
    unsigned u1 = (unsigned)f2bf(rA.z) | ((unsigned)f2bf(rA.w) << 16);
    *reinterpret_cast<uint2*>(dst + ag * 1024 + arow * 16 + ah * 8) = make_uint2(u0, u1);
  };

  auto computeT = [&](const char* bufA, const char* bufB) {
    bf16x8 af[4], bf[4];
#pragma unroll
    for (int m = 0; m < 4; ++m)
      af[m] = *reinterpret_cast<const bf16x8*>(bufA + g * 1024 + (m * 16 + qq) * 16);
#pragma unroll
    for (int n = 0; n < 4; ++n)
      bf[n] = *reinterpret_cast<const bf16x8*>(bufB + g * 8192 + (w * 64 + n * 16 + qq) * 16);
#pragma unroll
    for (int m = 0; m < 4; ++m)
#pragma unroll
      for (int n = 0; n < 4; ++n)
        acc[m][n] = __builtin_amdgcn_mfma_f32_16x16x32_bf16(af[m], bf[n], acc[m][n], 0, 0, 0);
  };

  // prologue
  issueA(0);
  stageB(bB0, 0);
  writeA(bA0);
  __syncthreads();

  for (int ks = 0; ks < 32; ++ks) {
    char* cA = (ks & 1) ? bA1 : bA0;
    char* cB = (ks & 1) ? bB1 : bB0;
    char* nA = (ks & 1) ? bA0 : bA1;
    char* nB = (ks & 1) ? bB0 : bB1;
    if (ks < 31) {
      issueA(ks + 1);      // f32 loads issued early (T14)
      stageB(nB, ks + 1);
    }
    computeT(cA, cB);
    if (ks < 31) writeA(nA);  // cvt + ds_write late
    __syncthreads();
  }

  // ---- epilogue: conv over j (K=31) in f32 ----
  float bqv[4];
#pragma unroll
  for (int n = 0; n < 4; ++n) {
    int c = w * 64 + n * 16 + qq;
    int h = c >> 5, j = c & 31;
    bqv[n] = (j < KK) ? bq[h * KK + j] : 0.f;
  }
  float cb[2] = {convb[w * 2], convb[w * 2 + 1]};

  // stage ksum slice rows [t0-15, t0+80] x 16 heads (stride 17 vs banks)
  float* kl = reinterpret_cast<float*>(smem);
  for (int i = tid; i < 96 * 16; i += 512) {
    int trow = i >> 4, h = i & 15;
    int t = t0 + trow - 15;
    kl[trow * 17 + h] = (t >= 0 && t < SS) ? ksum[((size_t)bb * SS + t) * HH + h] : 0.f;
  }
  __syncthreads();

#pragma unroll
  for (int m = 0; m < 4; ++m) {
    float part[4][2];
#pragma unroll
    for (int r = 0; r < 4; ++r) {
      part[r][0] = 0.f;
      part[r][1] = 0.f;
    }
#pragma unroll
    for (int n = 0; n < 4; ++n) {
      const int hp = n >> 1;
      const int j = (n & 1) * 16 + qq;  // j==31 has zero weight (padded col)
      const int h = w * 2 + hp;
#pragma unroll
      for (int r = 0; r < 4; ++r) {
        const int tl = m * 16 + g * 4 + r;
        part[r][hp] += (acc[m][n][r] + bqv[n]) * kl[(tl + j) * 17 + h];
      }
    }
#pragma unroll
    for (int r = 0; r < 4; ++r)
#pragma unroll
      for (int hp = 0; hp < 2; ++hp) {
        float v = part[r][hp];
        v += __shfl_xor(v, 1);
        v += __shfl_xor(v, 2);
        v += __shfl_xor(v, 4);
        v += __shfl_xor(v, 8);
        part[r][hp] = v;
      }
    if (qq < 4) {  // lane qq writes row r=qq of this (m,g) for both heads
      const int r = qq;
      const int t = t0 + m * 16 + g * 4 + r;
#pragma unroll
      for (int hp = 0; hp < 2; ++hp)
        out[((size_t)bb * HH + w * 2 + hp) * SS + t] = part[r][hp] + cb[hp];
    }
  }
}

extern "C" void kernel_launch(void* const* d_in, const int* in_sizes, int n_in,
                              void* d_out, int out_size, void* d_ws, size_t ws_size,
                              hipStream_t stream) {
  const float* q   = (const float*)d_in[0];
  const float* key = (const float*)d_in[1];
  // d_in[2] (values) and d_in[3] (lengths) are unused by the reference
  const float* Wq  = (const float*)d_in[4];
  const float* bq  = (const float*)d_in[5];
  const float* cvb = (const float*)d_in[6];
  float* out = (float*)d_out;

  float* ksum = (float*)d_ws;                                        // 2 MB f32
  unsigned short* Bimg = (unsigned short*)((char*)d_ws + 2097152);   // 1 MB bf16

  hipFuncSetAttribute((const void*)mca_kernel,
                      hipFuncAttributeMaxDynamicSharedMemorySize, 73728);

  prep_kernel<<<2048, 256, 0, stream>>>(Wq, Bimg);
  ksum_kernel<<<BB * SS, 256, 0, stream>>>(key, ksum);
  mca_kernel<<<BB * (SS / 64), 512, 73728, stream>>>(q, bq, cvb, ksum, Bimg, out);
}

// Round 3
// 79.058 us; speedup vs baseline: 1.1278x; 1.1278x over previous
//
#include <hip/hip_runtime.h>
#include <hip/hip_bf16.h>

#define BB 16
#define SS 2048
#define DD 1024
#define HH 16
#define KK 31
#define HK 496

typedef float f32x4 __attribute__((ext_vector_type(4)));
typedef __bf16 bf16x8 __attribute__((ext_vector_type(8)));

__device__ __forceinline__ unsigned short f2bf(float x) {
  unsigned u = __float_as_uint(x);
  unsigned r = u + 0x7FFFu + ((u >> 16) & 1u);
  return (unsigned short)(r >> 16);
}

// ---------------- prep: W_q (f32, D x 496) -> bf16 image, padded N=512.
// Layout for direct per-wave fragment loads:
// Bimg[ks][w][n][g][qq][e] = W[k=ks*32+g*8+e][col=w*64+n*16+qq]
__global__ void prep_kernel(const float* __restrict__ Wq,
                            unsigned short* __restrict__ Bimg) {
  int idx = blockIdx.x * 256 + threadIdx.x;  // < 32*8*4*4*16*8 = 524288
  int e = idx & 7;
  int qq = (idx >> 3) & 15;
  int g = (idx >> 7) & 3;
  int n = (idx >> 9) & 3;
  int w = (idx >> 11) & 7;
  int ks = idx >> 14;
  int k = ks * 32 + g * 8 + e;
  int c = w * 64 + n * 16 + qq;
  int h = c >> 5, j = c & 31;
  float v = (j < KK) ? Wq[k * HK + h * KK + j] : 0.f;
  Bimg[idx] = f2bf(v);
}

// ---------------- ksum: (B,S,H) = sum over 64 channels per head, f32
__global__ void ksum_kernel(const float* __restrict__ key,
                            float* __restrict__ ksum) {
  const int row = blockIdx.x;   // b*S + s
  const int tid = threadIdx.x;  // 0..255, 4 channels each
  const float4 v = reinterpret_cast<const float4*>(key + (size_t)row * DD)[tid];
  float p = v.x + v.y + v.z + v.w;
  p += __shfl_xor(p, 1);
  p += __shfl_xor(p, 2);
  p += __shfl_xor(p, 4);
  p += __shfl_xor(p, 8);
  if ((tid & 15) == 0) ksum[(size_t)row * HH + (tid >> 4)] = p;
}

// ---------------- fused GEMM (bf16 MFMA) + per-position conv + transpose
// BM=64, BN=512, BK=32, 8 waves (N-split). A: tiny LDS dbuf (8KB static).
// B: direct global->VGPR per wave (no LDS, no barrier coupling).
__global__ __launch_bounds__(512, 4) void mca_kernel(
    const float* __restrict__ q, const float* __restrict__ bq,
    const float* __restrict__ convb, const float* __restrict__ ksum,
    const unsigned short* __restrict__ Bimg, float* __restrict__ out) {
  __shared__ char smem[8192];
  const int tid = threadIdx.x;
  const int w = tid >> 6, lane = tid & 63;
  const int g = lane >> 4, qq = lane & 15;
  const int bid = blockIdx.x;
  const int bb = bid >> 5;
  const int t0 = (bid & 31) << 6;

  char* const bA0 = smem;
  char* const bA1 = smem + 4096;

  const float* qblk = q + ((size_t)(bb * SS + t0)) * DD;
  // per-wave B fragment stream base (16B per lane, 1KB per (n))
  const unsigned short* bbase = Bimg + w * 2048 + lane * 8;

  f32x4 acc[4][4];
#pragma unroll
  for (int m = 0; m < 4; ++m)
#pragma unroll
    for (int n = 0; n < 4; ++n) acc[m][n] = (f32x4){0.f, 0.f, 0.f, 0.f};

  // A staging: thread -> (row, 16B quarter-row)
  const int arow = tid >> 3;
  const int apart = tid & 7;
  const int ag = apart >> 1, ah = apart & 1;

  auto issueA = [&](int ks, float4& rA) {
    rA = *reinterpret_cast<const float4*>(qblk + (size_t)arow * DD + ks * 32 + apart * 4);
  };
  auto writeA = [&](char* dst, const float4& rA) {
    unsigned u0 = (unsigned)f2bf(rA.x) | ((unsigned)f2bf(rA.y) << 16);
    unsigned u1 = (unsigned)f2bf(rA.z) | ((unsigned)f2bf(rA.w) << 16);
    *reinterpret_cast<uint2*>(dst + ag * 1024 + arow * 16 + ah * 8) = make_uint2(u0, u1);
  };
  auto loadB = [&](int ks, bf16x8* pB) {
    const unsigned short* p = bbase + (size_t)ks * 16384;
#pragma unroll
    for (int n = 0; n < 4; ++n)
      pB[n] = *reinterpret_cast<const bf16x8*>(p + n * 512);
  };
  auto computeT = [&](const char* bufA, const bf16x8* pB) {
    bf16x8 af[4];
#pragma unroll
    for (int m = 0; m < 4; ++m)
      af[m] = *reinterpret_cast<const bf16x8*>(bufA + g * 1024 + (m * 16 + qq) * 16);
#pragma unroll
    for (int m = 0; m < 4; ++m)
#pragma unroll
      for (int n = 0; n < 4; ++n)
        acc[m][n] = __builtin_amdgcn_mfma_f32_16x16x32_bf16(af[m], pB[n], acc[m][n], 0, 0, 0);
  };
  auto barrier = [&]() {
    asm volatile("s_waitcnt lgkmcnt(0)" ::: "memory");
    __builtin_amdgcn_s_barrier();
  };

  float4 rA0, rA1;
  bf16x8 pB_a[4], pB_b[4];

  // prologue: stage A(0), load B(0)
  issueA(0, rA0);
  loadB(0, pB_a);
  writeA(bA0, rA0);
  barrier();

  // main loop: 2 steps per iter; prefetch loads stay in flight across barriers
  for (int ks2 = 0; ks2 < 15; ++ks2) {
    const int ks = ks2 * 2;
    // even step ks: compute(bA0, pB_a), prefetch ks+1 -> rA1/pB_b
    issueA(ks + 1, rA1);
    loadB(ks + 1, pB_b);
    computeT(bA0, pB_a);
    writeA(bA1, rA1);
    barrier();
    // odd step ks+1: compute(bA1, pB_b), prefetch ks+2 -> rA0/pB_a
    issueA(ks + 2, rA0);
    loadB(ks + 2, pB_a);
    computeT(bA1, pB_b);
    writeA(bA0, rA0);
    barrier();
  }
  // ks=30 (even): prefetch 31
  issueA(31, rA1);
  loadB(31, pB_b);
  computeT(bA0, pB_a);
  writeA(bA1, rA1);
  barrier();
  // ks=31
  computeT(bA1, pB_b);

  // ---- epilogue: conv over j (K=31) in f32 ----
  float bqv[4];
#pragma unroll
  for (int n = 0; n < 4; ++n) {
    int c = w * 64 + n * 16 + qq;
    int h = c >> 5, j = c & 31;
    bqv[n] = (j < KK) ? bq[h * KK + j] : 0.f;
  }
  float cb[2] = {convb[w * 2], convb[w * 2 + 1]};

  __syncthreads();  // A buffers dead; reuse smem for ksum slice
  float* kl = reinterpret_cast<float*>(smem);
  for (int i = tid; i < 96 * 16; i += 512) {
    int trow = i >> 4, h = i & 15;
    int t = t0 + trow - 15;
    kl[trow * 17 + h] = (t >= 0 && t < SS) ? ksum[((size_t)bb * SS + t) * HH + h] : 0.f;
  }
  __syncthreads();

#pragma unroll
  for (int m = 0; m < 4; ++m) {
    float part[4][2];
#pragma unroll
    for (int r = 0; r < 4; ++r) {
      part[r][0] = 0.f;
      part[r][1] = 0.f;
    }
#pragma unroll
    for (int n = 0; n < 4; ++n) {
      const int hp = n >> 1;
      const int j = (n & 1) * 16 + qq;  // j==31 has zero weight (padded col)
      const int h = w * 2 + hp;
#pragma unroll
      for (int r = 0; r < 4; ++r) {
        const int tl = m * 16 + g * 4 + r;
        part[r][hp] += (acc[m][n][r] + bqv[n]) * kl[(tl + j) * 17 + h];
      }
    }
#pragma unroll
    for (int r = 0; r < 4; ++r)
#pragma unroll
      for (int hp = 0; hp < 2; ++hp) {
        float v = part[r][hp];
        v += __shfl_xor(v, 1);
        v += __shfl_xor(v, 2);
        v += __shfl_xor(v, 4);
        v += __shfl_xor(v, 8);
        part[r][hp] = v;
      }
    if (qq < 4) {
      const int r = qq;
      const int t = t0 + m * 16 + g * 4 + r;
#pragma unroll
      for (int hp = 0; hp < 2; ++hp)
        out[((size_t)bb * HH + w * 2 + hp) * SS + t] = part[r][hp] + cb[hp];
    }
  }
}

extern "C" void kernel_launch(void* const* d_in, const int* in_sizes, int n_in,
                              void* d_out, int out_size, void* d_ws, size_t ws_size,
                              hipStream_t stream) {
  const float* q   = (const float*)d_in[0];
  const float* key = (const float*)d_in[1];
  // d_in[2] (values) and d_in[3] (lengths) are unused by the reference
  const float* Wq  = (const float*)d_in[4];
  const float* bq  = (const float*)d_in[5];
  const float* cvb = (const float*)d_in[6];
  float* out = (float*)d_out;

  float* ksum = (float*)d_ws;                                        // 2 MB f32
  unsigned short* Bimg = (unsigned short*)((char*)d_ws + 2097152);   // 1 MB bf16

  prep_kernel<<<2048, 256, 0, stream>>>(Wq, Bimg);
  ksum_kernel<<<BB * SS, 256, 0, stream>>>(key, ksum);
  mca_kernel<<<BB * (SS / 64), 512, 0, stream>>>(q, bq, cvb, ksum, Bimg, out);
}